// Round 3
// baseline (1225.235 us; speedup 1.0000x reference)
//
#include <hip/hip_runtime.h>

#define SEQ_LEN 96
#define PRED_LEN 16
#define HIDDEN 64
#define FEAT 7
#define BATCH 512
#define GATES 256                 // 4*HIDDEN
#define TL (SEQ_LEN + PRED_LEN)   // 112-entry sliding timeline
#define XSTR 8                    // padded timeline stride (2x float4 loads)

__device__ __forceinline__ float sigmoidf_(float x) {
    return 1.0f / (1.0f + __expf(-x));
}
__device__ __forceinline__ float tanhf_(float x) {
    return 1.0f - 2.0f / (__expf(2.0f * x) + 1.0f);
}
// register->register cross-lane broadcast: VALU pipe, no LDS
__device__ __forceinline__ float rlane(float v, int l) {
    return __int_as_float(__builtin_amdgcn_readlane(__float_as_int(v), l));
}

// One block (256 threads = 4 waves) per batch element. Thread g owns gate g
// (whh row in 64 VGPRs). h and c live DISTRIBUTED IN REGISTERS: lane j of
// every wave holds h_j and c_j (4 redundant replicas). The h-dot broadcasts
// h_j to all lanes via v_readlane (VALU), so the hot loop's only LDS traffic
// is the 256-float gate exchange (1 write + 4 reads) and 2 x-reads per step,
// with ONE barrier per step (parity-double-buffered gate array).
// amdgpu_waves_per_eu(2,2): grid is 512 blocks = 2 blocks/CU max, so don't
// let the allocator shrink below 256 VGPRs and spill whh.
__global__ __launch_bounds__(256)
__attribute__((amdgpu_waves_per_eu(2, 2)))
void lstm_ar_kernel(
    const float* __restrict__ x,     // [B, 96, 7]
    const float* __restrict__ W_ih,  // [256, 7]
    const float* __restrict__ W_hh,  // [256, 64]
    const float* __restrict__ b_ih,  // [256]
    const float* __restrict__ b_hh,  // [256]
    const float* __restrict__ fc_W,  // [7, 64]
    const float* __restrict__ fc_b,  // [7]
    float* __restrict__ out)         // [B, 16, 7]
{
    __shared__ float xs[TL * XSTR];       // padded sliding input timeline
    __shared__ float gbuf[2][GATES];      // parity double-buffered gates
    __shared__ float fcw[FEAT * HIDDEN];
    __shared__ float fcb[FEAT];

    const int tid  = threadIdx.x;
    const int b    = blockIdx.x;
    const int wv   = tid >> 6;            // wave id = gate class (i,f,g,o)
    const int lane = tid & 63;

    // ---- per-thread weight registers ----
    float whh[HIDDEN];
    {
        const float4* wrow = (const float4*)(W_hh + tid * HIDDEN);  // 256B-aligned
        #pragma unroll
        for (int j = 0; j < 16; ++j) {
            float4 v = wrow[j];
            whh[4*j+0] = v.x; whh[4*j+1] = v.y; whh[4*j+2] = v.z; whh[4*j+3] = v.w;
        }
    }
    float wih[FEAT];
    #pragma unroll
    for (int i = 0; i < FEAT; ++i) wih[i] = W_ih[tid * FEAT + i];
    const float bias = b_ih[tid] + b_hh[tid];

    // ---- stage inputs / init state ----
    for (int i = tid; i < SEQ_LEN * FEAT; i += 256) {
        int t = i / FEAT, f = i - t * FEAT;
        xs[t * XSTR + f] = x[b * SEQ_LEN * FEAT + i];
    }
    for (int i = tid; i < FEAT * HIDDEN; i += 256) fcw[i] = fc_W[i];
    if (tid < FEAT) fcb[tid] = fc_b[tid];
    float hreg = 0.0f;                    // lane j holds h_j (per-wave replica)
    float c    = 0.0f;                    // lane j holds c_j
    __syncthreads();

    int p = 0;                            // gate-buffer parity
    for (int k = 0; k < PRED_LEN; ++k) {
        for (int t = 0; t < SEQ_LEN; ++t) {
            const float4* xt4 = (const float4*)(xs + (k + t) * XSTR);
            float4 xa = xt4[0];
            float4 xb = xt4[1];           // .w is padding

            float a0 = bias, a1 = 0.0f, a2 = 0.0f, a3 = 0.0f;
            a0 = fmaf(wih[0], xa.x, a0);
            a1 = fmaf(wih[1], xa.y, a1);
            a2 = fmaf(wih[2], xa.z, a2);
            a3 = fmaf(wih[3], xa.w, a3);
            a0 = fmaf(wih[4], xb.x, a0);
            a1 = fmaf(wih[5], xb.y, a1);
            a2 = fmaf(wih[6], xb.z, a2);

            // h-dot: broadcast h_j from lane j via readlane (no LDS)
            #pragma unroll
            for (int j = 0; j < HIDDEN; j += 4) {
                a0 = fmaf(whh[j + 0], rlane(hreg, j + 0), a0);
                a1 = fmaf(whh[j + 1], rlane(hreg, j + 1), a1);
                a2 = fmaf(whh[j + 2], rlane(hreg, j + 2), a2);
                a3 = fmaf(whh[j + 3], rlane(hreg, j + 3), a3);
            }
            float acc = (a0 + a1) + (a2 + a3);

            // PyTorch gate order i,f,g,o -> wave 2 is tanh (wave-uniform branch)
            float act = (wv == 2) ? tanhf_(acc) : sigmoidf_(acc);
            gbuf[p][tid] = act;
            __syncthreads();              // the ONLY barrier per step

            // replicated cell update: lane j of every wave updates c_j, h_j
            float ig = gbuf[p][lane];
            float fg = gbuf[p][HIDDEN     + lane];
            float gg = gbuf[p][2 * HIDDEN + lane];
            float og = gbuf[p][3 * HIDDEN + lane];
            c    = fmaf(fg, c, ig * gg);
            hreg = og * tanhf_(c);        // stays in a register
            p ^= 1;
        }

        // ---- prediction head: lanes 0-6 of wave 0; h via readlane ----
        if (tid < FEAT) {
            float p0 = fcb[tid], p1 = 0.0f, p2 = 0.0f, p3 = 0.0f;
            #pragma unroll
            for (int j = 0; j < HIDDEN; j += 4) {
                p0 = fmaf(fcw[tid * HIDDEN + j + 0], rlane(hreg, j + 0), p0);
                p1 = fmaf(fcw[tid * HIDDEN + j + 1], rlane(hreg, j + 1), p1);
                p2 = fmaf(fcw[tid * HIDDEN + j + 2], rlane(hreg, j + 2), p2);
                p3 = fmaf(fcw[tid * HIDDEN + j + 3], rlane(hreg, j + 3), p3);
            }
            float pred = (p0 + p1) + (p2 + p3);
            out[(b * PRED_LEN + k) * FEAT + tid] = pred;
            xs[(SEQ_LEN + k) * XSTR + tid] = pred;    // append to timeline
        }
        __syncthreads();                  // pred visible before consumption
    }
}

extern "C" void kernel_launch(void* const* d_in, const int* in_sizes, int n_in,
                              void* d_out, int out_size, void* d_ws, size_t ws_size,
                              hipStream_t stream) {
    const float* x    = (const float*)d_in[0];
    const float* W_ih = (const float*)d_in[1];
    const float* W_hh = (const float*)d_in[2];
    const float* b_ih = (const float*)d_in[3];
    const float* b_hh = (const float*)d_in[4];
    const float* fc_W = (const float*)d_in[5];
    const float* fc_b = (const float*)d_in[6];
    float* out = (float*)d_out;

    lstm_ar_kernel<<<BATCH, 256, 0, stream>>>(x, W_ih, W_hh, b_ih, b_hh, fc_W, fc_b, out);
}

// Round 4
// 1023.372 us; speedup vs baseline: 1.1973x; 1.1973x over previous
//
#include <hip/hip_runtime.h>

#define SEQ_LEN 96
#define PRED_LEN 16
#define HIDDEN 64
#define FEAT 7
#define BATCH 512
#define TL (SEQ_LEN + PRED_LEN)   // 112-row sliding timeline
#define XSTR 8                    // padded row stride (2x float4)

// swap adjacent lane pairs (0<->1, 2<->3, ...): quad_perm [1,0,3,2] = 0xB1.
// Pure VALU (DPP) -- no LDS pipe, no readlane.
__device__ __forceinline__ float dpp_pairswap(float v) {
    return __int_as_float(__builtin_amdgcn_mov_dpp(__float_as_int(v), 0xB1, 0xF, 0xF, true));
}

// Layout: block = 256 threads = 2 batch elements (128 threads each).
// Thread (u, s): owns ALL FOUR gates (i,f,g,o) of hidden unit u, over K-half s
// (h[32s:32s+32]). whh slice = 4x32 floats in VGPRs. Partner lanes are
// ADJACENT (lane 2i <-> 2i+1), partials combined via one DPP-add per gate, so
// the cell update (c_u, h_u) is fully in-lane. Per step LDS: 8 broadcast
// b128 h-reads + 1 b128 x-read + 1 b32 h-write; ONE barrier (parity h).
__global__ __launch_bounds__(256)
__attribute__((amdgpu_waves_per_eu(1, 1)))
void lstm_ar_kernel(
    const float* __restrict__ x,     // [B, 96, 7]
    const float* __restrict__ W_ih,  // [256, 7]
    const float* __restrict__ W_hh,  // [256, 64]
    const float* __restrict__ b_ih,  // [256]
    const float* __restrict__ b_hh,  // [256]
    const float* __restrict__ fc_W,  // [7, 64]
    const float* __restrict__ fc_b,  // [7]
    float* __restrict__ out)         // [B, 16, 7]
{
    __shared__ float xs[2][TL * XSTR];     // per-batch padded timeline (pad=0)
    __shared__ float hbuf[2][2][HIDDEN];   // [batch][parity][unit]
    __shared__ float fcw[FEAT * HIDDEN];
    __shared__ float fcb[FEAT];

    const int tid  = threadIdx.x;
    const int bb   = tid >> 7;                          // batch-in-block (wave-pair aligned)
    const int lane = tid & 63;
    const int loc  = tid & 127;                         // thread-in-batch
    const int u    = ((loc >> 6) << 5) + (lane >> 1);   // hidden unit 0..63
    const int s    = lane & 1;                          // K-half
    const int b    = blockIdx.x * 2 + bb;               // global batch

    // ---- per-thread weights: gate g row = u + 64g, K-cols 32s..32s+31 ----
    float whh[4][32];
    #pragma unroll
    for (int g = 0; g < 4; ++g) {
        const float4* wr = (const float4*)(W_hh + (u + (g << 6)) * HIDDEN + (s << 5));
        #pragma unroll
        for (int j = 0; j < 8; ++j) {
            float4 v = wr[j];
            whh[g][4*j+0] = v.x; whh[g][4*j+1] = v.y;
            whh[g][4*j+2] = v.z; whh[g][4*j+3] = v.w;
        }
    }
    float wih[4][4];   // x-cols 4s..4s+3 (col 7 -> zero weight, eats the pad)
    #pragma unroll
    for (int g = 0; g < 4; ++g)
        #pragma unroll
        for (int i = 0; i < 4; ++i) {
            int col = (s << 2) + i;
            wih[g][i] = (col < FEAT) ? W_ih[(u + (g << 6)) * FEAT + col] : 0.0f;
        }
    float bias[4];     // only the s=0 partner carries the bias
    #pragma unroll
    for (int g = 0; g < 4; ++g)
        bias[g] = (s == 0) ? (b_ih[u + (g << 6)] + b_hh[u + (g << 6)]) : 0.0f;

    // ---- stage timeline (pads + future rows zeroed), fc, h init ----
    for (int i = tid; i < 2 * TL * XSTR; i += 256) {
        int bloc = i / (TL * XSTR);
        int rem  = i - bloc * (TL * XSTR);
        int row  = rem >> 3, f = rem & 7;
        float v = 0.0f;
        if (row < SEQ_LEN && f < FEAT)
            v = x[(blockIdx.x * 2 + bloc) * SEQ_LEN * FEAT + row * FEAT + f];
        xs[bloc][rem] = v;
    }
    for (int i = tid; i < FEAT * HIDDEN; i += 256) fcw[i] = fc_W[i];
    if (tid < FEAT) fcb[tid] = fc_b[tid];
    if (loc < HIDDEN) hbuf[bb][0][loc] = 0.0f;
    float c = 0.0f;                       // c_u replica (both partners)
    __syncthreads();

    int p = 0;
    for (int k = 0; k < PRED_LEN; ++k) {
        #pragma unroll 2
        for (int t = 0; t < SEQ_LEN; ++t) {
            const int row = k + t;
            float4 xv = *(const float4*)&xs[bb][row * XSTR + (s << 2)];
            const float4* h4 = (const float4*)&hbuf[bb][p][s << 5];

            float a0 = bias[0], a1 = bias[1], a2 = bias[2], a3 = bias[3];
            a0 = fmaf(wih[0][0], xv.x, a0); a1 = fmaf(wih[1][0], xv.x, a1);
            a2 = fmaf(wih[2][0], xv.x, a2); a3 = fmaf(wih[3][0], xv.x, a3);
            a0 = fmaf(wih[0][1], xv.y, a0); a1 = fmaf(wih[1][1], xv.y, a1);
            a2 = fmaf(wih[2][1], xv.y, a2); a3 = fmaf(wih[3][1], xv.y, a3);
            a0 = fmaf(wih[0][2], xv.z, a0); a1 = fmaf(wih[1][2], xv.z, a1);
            a2 = fmaf(wih[2][2], xv.z, a2); a3 = fmaf(wih[3][2], xv.z, a3);
            a0 = fmaf(wih[0][3], xv.w, a0); a1 = fmaf(wih[1][3], xv.w, a1);
            a2 = fmaf(wih[2][3], xv.w, a2); a3 = fmaf(wih[3][3], xv.w, a3);

            #pragma unroll
            for (int j = 0; j < 8; ++j) {
                float4 hv = h4[j];
                a0 = fmaf(whh[0][4*j+0], hv.x, a0);
                a1 = fmaf(whh[1][4*j+0], hv.x, a1);
                a2 = fmaf(whh[2][4*j+0], hv.x, a2);
                a3 = fmaf(whh[3][4*j+0], hv.x, a3);
                a0 = fmaf(whh[0][4*j+1], hv.y, a0);
                a1 = fmaf(whh[1][4*j+1], hv.y, a1);
                a2 = fmaf(whh[2][4*j+1], hv.y, a2);
                a3 = fmaf(whh[3][4*j+1], hv.y, a3);
                a0 = fmaf(whh[0][4*j+2], hv.z, a0);
                a1 = fmaf(whh[1][4*j+2], hv.z, a1);
                a2 = fmaf(whh[2][4*j+2], hv.z, a2);
                a3 = fmaf(whh[3][4*j+2], hv.z, a3);
                a0 = fmaf(whh[0][4*j+3], hv.w, a0);
                a1 = fmaf(whh[1][4*j+3], hv.w, a1);
                a2 = fmaf(whh[2][4*j+3], hv.w, a2);
                a3 = fmaf(whh[3][4*j+3], hv.w, a3);
            }

            // combine K-halves: partner-lane sum via DPP (both lanes get total)
            a0 += dpp_pairswap(a0);
            a1 += dpp_pairswap(a1);
            a2 += dpp_pairswap(a2);
            a3 += dpp_pairswap(a3);

            float gi = 1.0f / (1.0f + __expf(-a0));
            float gf = 1.0f / (1.0f + __expf(-a1));
            float gg = 1.0f - 2.0f / (__expf(2.0f * a2) + 1.0f);
            float go = 1.0f / (1.0f + __expf(-a3));
            c = fmaf(gf, c, gi * gg);
            float h = go * (1.0f - 2.0f / (__expf(2.0f * c) + 1.0f));

            if (s == 0) hbuf[bb][p ^ 1][u] = h;   // publish new h (parity flip)
            p ^= 1;
            __syncthreads();                       // the ONLY barrier per step
        }

        // ---- prediction head: lanes 0..6 of wave 0 (batch 0) / wave 2 (batch 1) ----
        if (loc < FEAT) {
            float p0 = fcb[loc], p1 = 0.0f, p2 = 0.0f, p3 = 0.0f;
            const float* hh = hbuf[bb][p];
            #pragma unroll
            for (int j = 0; j < HIDDEN; j += 4) {
                p0 = fmaf(fcw[loc * HIDDEN + j + 0], hh[j + 0], p0);
                p1 = fmaf(fcw[loc * HIDDEN + j + 1], hh[j + 1], p1);
                p2 = fmaf(fcw[loc * HIDDEN + j + 2], hh[j + 2], p2);
                p3 = fmaf(fcw[loc * HIDDEN + j + 3], hh[j + 3], p3);
            }
            float pred = (p0 + p1) + (p2 + p3);
            out[(b * PRED_LEN + k) * FEAT + loc] = pred;
            xs[bb][(SEQ_LEN + k) * XSTR + loc] = pred;   // append (pad slot stays 0)
        }
        __syncthreads();
    }
}

extern "C" void kernel_launch(void* const* d_in, const int* in_sizes, int n_in,
                              void* d_out, int out_size, void* d_ws, size_t ws_size,
                              hipStream_t stream) {
    const float* x    = (const float*)d_in[0];
    const float* W_ih = (const float*)d_in[1];
    const float* W_hh = (const float*)d_in[2];
    const float* b_ih = (const float*)d_in[3];
    const float* b_hh = (const float*)d_in[4];
    const float* fc_W = (const float*)d_in[5];
    const float* fc_b = (const float*)d_in[6];
    float* out = (float*)d_out;

    lstm_ar_kernel<<<BATCH / 2, 256, 0, stream>>>(x, W_ih, W_hh, b_ih, b_hh, fc_W, fc_b, out);
}

// Round 5
// 989.040 us; speedup vs baseline: 1.2388x; 1.0347x over previous
//
#include <hip/hip_runtime.h>

#define SEQ_LEN 96
#define PRED_LEN 16
#define HIDDEN 64
#define FEAT 7
#define BATCH 512
#define TL (SEQ_LEN + PRED_LEN)   // 112-row sliding timeline
#define XSTR 8                    // padded row stride

// DPP quad-perm butterflies (pure VALU, no LDS pipe):
__device__ __forceinline__ float qp_xor1(float v) {  // swap lane^1 in quads
    return __int_as_float(__builtin_amdgcn_mov_dpp(__float_as_int(v), 0xB1, 0xF, 0xF, true));
}
__device__ __forceinline__ float qp_xor2(float v) {  // swap lane^2 in quads
    return __int_as_float(__builtin_amdgcn_mov_dpp(__float_as_int(v), 0x4E, 0xF, 0xF, true));
}

// Block = 256 threads = ONE batch element; grid = 512, 2 blocks/CU, 8 waves/CU.
// Thread (u = tid>>2, s = tid&3): all 4 gates of unit u over K-quarter s
// (h[16s..16s+16)). Only 64 weight floats/thread (~110 VGPR pressure) so the
// allocator can actually keep them resident (128-float versions kept getting
// demoted, rounds 2+4). K-reduce = 2 DPP quad-perm butterfly rounds; cell
// update fully in-lane (c replicated x4, deterministic). Per-step LDS: 4 b128
// h-reads + 1 b64 x-read + 1 b32 h-write, ONE barrier (parity h ping-pong).
__global__ __launch_bounds__(256)
__attribute__((amdgpu_waves_per_eu(2, 2)))
void lstm_ar_kernel(
    const float* __restrict__ x,     // [B, 96, 7]
    const float* __restrict__ W_ih,  // [256, 7]
    const float* __restrict__ W_hh,  // [256, 64]
    const float* __restrict__ b_ih,  // [256]
    const float* __restrict__ b_hh,  // [256]
    const float* __restrict__ fc_W,  // [7, 64]
    const float* __restrict__ fc_b,  // [7]
    float* __restrict__ out)         // [B, 16, 7]
{
    __shared__ float xs[TL * XSTR];   // padded sliding timeline (pad slot = 0)
    __shared__ float hb[2][HIDDEN];   // parity ping-pong h
    __shared__ float fcw[FEAT * HIDDEN];
    __shared__ float fcb[FEAT];

    const int tid = threadIdx.x;
    const int b   = blockIdx.x;
    const int u   = tid >> 2;         // hidden unit 0..63
    const int s   = tid & 3;          // K-quarter

    // ---- per-thread weights: 4 gates x 16 K-cols ----
    float whh[4][16];
    #pragma unroll
    for (int g = 0; g < 4; ++g) {
        const float4* wr = (const float4*)(W_hh + (u + (g << 6)) * HIDDEN + (s << 4));
        #pragma unroll
        for (int j = 0; j < 4; ++j) {
            float4 v = wr[j];
            whh[g][4*j+0] = v.x; whh[g][4*j+1] = v.y;
            whh[g][4*j+2] = v.z; whh[g][4*j+3] = v.w;
        }
    }
    float wih[4][2];                  // x-cols 2s, 2s+1 (col 7 -> 0, eats pad)
    #pragma unroll
    for (int g = 0; g < 4; ++g)
        #pragma unroll
        for (int i = 0; i < 2; ++i) {
            int col = (s << 1) + i;
            wih[g][i] = (col < FEAT) ? W_ih[(u + (g << 6)) * FEAT + col] : 0.0f;
        }
    float binit[4];                   // bias folded into s==0's partial only
    #pragma unroll
    for (int g = 0; g < 4; ++g)
        binit[g] = (s == 0) ? (b_ih[u + (g << 6)] + b_hh[u + (g << 6)]) : 0.0f;

    // ---- stage timeline / fc / init ----
    for (int i = tid; i < TL * XSTR; i += 256) {
        int row = i >> 3, f = i & 7;
        float v = 0.0f;
        if (row < SEQ_LEN && f < FEAT) v = x[b * SEQ_LEN * FEAT + row * FEAT + f];
        xs[i] = v;
    }
    for (int i = tid; i < FEAT * HIDDEN; i += 256) fcw[i] = fc_W[i];
    if (tid < FEAT)   fcb[tid] = fc_b[tid];
    if (tid < HIDDEN) hb[0][tid] = 0.0f;
    float c = 0.0f;                   // c_u, replicated in the 4 quad lanes
    __syncthreads();

    int p = 0;
    for (int k = 0; k < PRED_LEN; ++k) {
        for (int t = 0; t < SEQ_LEN; ++t) {
            float2 xv = *(const float2*)&xs[(k + t) * XSTR + (s << 1)];
            const float4* h4 = (const float4*)&hb[p][s << 4];

            float a0 = binit[0], a1 = binit[1], a2 = binit[2], a3 = binit[3];
            a0 = fmaf(wih[0][0], xv.x, a0); a1 = fmaf(wih[1][0], xv.x, a1);
            a2 = fmaf(wih[2][0], xv.x, a2); a3 = fmaf(wih[3][0], xv.x, a3);
            a0 = fmaf(wih[0][1], xv.y, a0); a1 = fmaf(wih[1][1], xv.y, a1);
            a2 = fmaf(wih[2][1], xv.y, a2); a3 = fmaf(wih[3][1], xv.y, a3);

            #pragma unroll
            for (int j = 0; j < 4; ++j) {
                float4 hv = h4[j];
                a0 = fmaf(whh[0][4*j+0], hv.x, a0);
                a1 = fmaf(whh[1][4*j+0], hv.x, a1);
                a2 = fmaf(whh[2][4*j+0], hv.x, a2);
                a3 = fmaf(whh[3][4*j+0], hv.x, a3);
                a0 = fmaf(whh[0][4*j+1], hv.y, a0);
                a1 = fmaf(whh[1][4*j+1], hv.y, a1);
                a2 = fmaf(whh[2][4*j+1], hv.y, a2);
                a3 = fmaf(whh[3][4*j+1], hv.y, a3);
                a0 = fmaf(whh[0][4*j+2], hv.z, a0);
                a1 = fmaf(whh[1][4*j+2], hv.z, a1);
                a2 = fmaf(whh[2][4*j+2], hv.z, a2);
                a3 = fmaf(whh[3][4*j+2], hv.z, a3);
                a0 = fmaf(whh[0][4*j+3], hv.w, a0);
                a1 = fmaf(whh[1][4*j+3], hv.w, a1);
                a2 = fmaf(whh[2][4*j+3], hv.w, a2);
                a3 = fmaf(whh[3][4*j+3], hv.w, a3);
            }

            // K-reduce across the quad: 2 butterfly rounds, all lanes get totals
            a0 += qp_xor1(a0); a1 += qp_xor1(a1);
            a2 += qp_xor1(a2); a3 += qp_xor1(a3);
            a0 += qp_xor2(a0); a1 += qp_xor2(a1);
            a2 += qp_xor2(a2); a3 += qp_xor2(a3);

            // PyTorch gate order i,f,g,o
            float gi = 1.0f / (1.0f + __expf(-a0));
            float gf = 1.0f / (1.0f + __expf(-a1));
            float gg = 1.0f - 2.0f / (__expf(2.0f * a2) + 1.0f);
            float go = 1.0f / (1.0f + __expf(-a3));
            c = fmaf(gf, c, gi * gg);
            float h = go * (1.0f - 2.0f / (__expf(2.0f * c) + 1.0f));

            if (s == 0) hb[p ^ 1][u] = h;     // one writer per unit
            p ^= 1;
            __syncthreads();                   // the ONLY barrier per step
        }

        // ---- prediction head: lanes 0..6 ----
        if (tid < FEAT) {
            float p0 = fcb[tid], p1 = 0.0f, p2 = 0.0f, p3 = 0.0f;
            const float4* hh = (const float4*)hb[p];
            #pragma unroll
            for (int j = 0; j < 16; ++j) {
                float4 hv = hh[j];
                p0 = fmaf(fcw[tid * HIDDEN + 4*j + 0], hv.x, p0);
                p1 = fmaf(fcw[tid * HIDDEN + 4*j + 1], hv.y, p1);
                p2 = fmaf(fcw[tid * HIDDEN + 4*j + 2], hv.z, p2);
                p3 = fmaf(fcw[tid * HIDDEN + 4*j + 3], hv.w, p3);
            }
            float pred = (p0 + p1) + (p2 + p3);
            out[(b * PRED_LEN + k) * FEAT + tid] = pred;
            xs[(SEQ_LEN + k) * XSTR + tid] = pred;   // append (pad slot stays 0)
        }
        __syncthreads();
    }
}

extern "C" void kernel_launch(void* const* d_in, const int* in_sizes, int n_in,
                              void* d_out, int out_size, void* d_ws, size_t ws_size,
                              hipStream_t stream) {
    const float* x    = (const float*)d_in[0];
    const float* W_ih = (const float*)d_in[1];
    const float* W_hh = (const float*)d_in[2];
    const float* b_ih = (const float*)d_in[3];
    const float* b_hh = (const float*)d_in[4];
    const float* fc_W = (const float*)d_in[5];
    const float* fc_b = (const float*)d_in[6];
    float* out = (float*)d_out;

    lstm_ar_kernel<<<BATCH, 256, 0, stream>>>(x, W_ih, W_hh, b_ih, b_hh, fc_W, fc_b, out);
}

// Round 6
// 614.706 us; speedup vs baseline: 1.9932x; 1.6090x over previous
//
#include <hip/hip_runtime.h>

#define SEQ_LEN 96
#define PRED_LEN 16
#define HIDDEN 64
#define FEAT 7
#define BATCH 512
#define TL (SEQ_LEN + PRED_LEN)   // 112-row sliding timeline
#define XSTR 8                    // padded row stride

typedef float v2f __attribute__((ext_vector_type(2)));

#define L2E 1.4426950408889634f

// DPP quad ops (pure VALU, no LDS pipe). Verified on HW rounds 4-5.
__device__ __forceinline__ float qp_xor1(float v) {  // swap lane^1 in quad
    return __int_as_float(__builtin_amdgcn_mov_dpp(__float_as_int(v), 0xB1, 0xF, 0xF, true));
}
__device__ __forceinline__ float qp_xor2(float v) {  // swap lane^2 in quad
    return __int_as_float(__builtin_amdgcn_mov_dpp(__float_as_int(v), 0x4E, 0xF, 0xF, true));
}
template <int CTRL>
__device__ __forceinline__ float qp_bcast(float v) { // broadcast quad-lane g
    return __int_as_float(__builtin_amdgcn_mov_dpp(__float_as_int(v), CTRL, 0xF, 0xF, true));
}

// Block = 256 threads = ONE batch; grid 512, 2 blocks/CU, 2 waves/SIMD.
// Thread (u = tid>>2, s = tid&3): all 4 gates of unit u, K-cols [16s,16s+16).
// Hot-loop instruction diet (the r5 lesson: we are VALU-ISSUE bound):
//  - K-packed v_pk_fma_f32 (36 pk ops replace 72 scalar FMAs); pk operands
//    come straight from LDS float4 reads + contiguous weight pairs.
//  - activations via v_rcp/v_exp2 (NO fp32 division: IEEE div = ~10 insts).
//  - each lane activates only ITS gate (branchless per-lane k/m/b consts:
//    sigma(a)=rcp(1+exp2(-a*L2E)), tanh(a)=2*rcp(1+exp2(-2a*L2E))-1),
//    then 4 DPP quad-broadcasts deliver canonical (i,f,g,o) to all lanes.
__global__ __launch_bounds__(256)
__attribute__((amdgpu_waves_per_eu(2, 2)))
void lstm_ar_kernel(
    const float* __restrict__ x,     // [B, 96, 7]
    const float* __restrict__ W_ih,  // [256, 7]
    const float* __restrict__ W_hh,  // [256, 64]
    const float* __restrict__ b_ih,  // [256]
    const float* __restrict__ b_hh,  // [256]
    const float* __restrict__ fc_W,  // [7, 64]
    const float* __restrict__ fc_b,  // [7]
    float* __restrict__ out)         // [B, 16, 7]
{
    __shared__ float xs[TL * XSTR];   // padded sliding timeline (pad slot = 0)
    __shared__ float hb0[HIDDEN];     // h ping-pong (even steps read hb0)
    __shared__ float hb1[HIDDEN];
    __shared__ float fcw[FEAT * HIDDEN];
    __shared__ float fcb[FEAT];

    const int tid = threadIdx.x;
    const int b   = blockIdx.x;
    const int u   = tid >> 2;         // hidden unit 0..63
    const int s   = tid & 3;          // K-quarter / gate-of-this-lane

    // ---- per-thread weights: 4 gates x 16 K-cols as 8 K-pairs (v2f) ----
    v2f wh[4][8];
    #pragma unroll
    for (int g = 0; g < 4; ++g) {
        const float* wr = W_hh + (u + (g << 6)) * HIDDEN + (s << 4);
        #pragma unroll
        for (int j = 0; j < 8; ++j) wh[g][j] = *(const v2f*)(wr + 2 * j);
    }
    v2f wx[4];                        // x-cols (2s, 2s+1); col 7 -> 0 (eats pad)
    #pragma unroll
    for (int g = 0; g < 4; ++g) {
        int c0 = (s << 1), c1 = (s << 1) + 1;
        wx[g].x = W_ih[(u + (g << 6)) * FEAT + c0];
        wx[g].y = (c1 < FEAT) ? W_ih[(u + (g << 6)) * FEAT + c1] : 0.0f;
    }
    v2f binit[4];                     // bias carried by s==0 only
    #pragma unroll
    for (int g = 0; g < 4; ++g) {
        binit[g].x = (s == 0) ? (b_ih[u + (g << 6)] + b_hh[u + (g << 6)]) : 0.0f;
        binit[g].y = 0.0f;
    }
    // per-lane activation constants (lane s activates gate s; gate 2 = tanh)
    const float actk = (s == 2) ? (-2.0f * L2E) : (-L2E);
    const float actm = (s == 2) ? 2.0f : 1.0f;
    const float actb = (s == 2) ? -1.0f : 0.0f;

    // ---- stage timeline / fc / init ----
    for (int i = tid; i < TL * XSTR; i += 256) {
        int row = i >> 3, f = i & 7;
        float v = 0.0f;
        if (row < SEQ_LEN && f < FEAT) v = x[b * SEQ_LEN * FEAT + row * FEAT + f];
        xs[i] = v;
    }
    for (int i = tid; i < FEAT * HIDDEN; i += 256) fcw[i] = fc_W[i];
    if (tid < FEAT)   fcb[tid] = fc_b[tid];
    if (tid < HIDDEN) hb0[tid] = 0.0f;
    float c = 0.0f;                   // c_u replica (identical in all 4 quad lanes)
    __syncthreads();

    auto step = [&](int row, const float* __restrict__ hr, float* __restrict__ hw) {
        v2f xv = *(const v2f*)&xs[row * XSTR + (s << 1)];
        const float4* h4 = (const float4*)(hr + (s << 4));

        v2f A0 = binit[0], A1 = binit[1], A2 = binit[2], A3 = binit[3];
        A0 = __builtin_elementwise_fma(wx[0], xv, A0);
        A1 = __builtin_elementwise_fma(wx[1], xv, A1);
        A2 = __builtin_elementwise_fma(wx[2], xv, A2);
        A3 = __builtin_elementwise_fma(wx[3], xv, A3);

        #pragma unroll
        for (int j = 0; j < 4; ++j) {
            float4 hv = h4[j];
            v2f hlo; hlo.x = hv.x; hlo.y = hv.y;
            v2f hhi; hhi.x = hv.z; hhi.y = hv.w;
            A0 = __builtin_elementwise_fma(wh[0][2*j],   hlo, A0);
            A1 = __builtin_elementwise_fma(wh[1][2*j],   hlo, A1);
            A2 = __builtin_elementwise_fma(wh[2][2*j],   hlo, A2);
            A3 = __builtin_elementwise_fma(wh[3][2*j],   hlo, A3);
            A0 = __builtin_elementwise_fma(wh[0][2*j+1], hhi, A0);
            A1 = __builtin_elementwise_fma(wh[1][2*j+1], hhi, A1);
            A2 = __builtin_elementwise_fma(wh[2][2*j+1], hhi, A2);
            A3 = __builtin_elementwise_fma(wh[3][2*j+1], hhi, A3);
        }

        // horizontal + quad butterfly: every lane gets all 4 gate sums
        float r0 = A0.x + A0.y, r1 = A1.x + A1.y;
        float r2 = A2.x + A2.y, r3 = A3.x + A3.y;
        r0 += qp_xor1(r0); r1 += qp_xor1(r1); r2 += qp_xor1(r2); r3 += qp_xor1(r3);
        r0 += qp_xor2(r0); r1 += qp_xor2(r1); r2 += qp_xor2(r2); r3 += qp_xor2(r3);

        // lane s activates gate s only (branchless, rcp+exp2)
        float ab = (s & 1) ? r1 : r0;
        float cd = (s & 1) ? r3 : r2;
        float a  = (s & 2) ? cd : ab;
        float e  = __builtin_amdgcn_exp2f(a * actk);
        float r  = __builtin_amdgcn_rcpf(1.0f + e);
        float act = fmaf(actm, r, actb);

        // broadcast canonical (i,f,g,o) to all quad lanes
        float gi = qp_bcast<0x00>(act);
        float gf = qp_bcast<0x55>(act);
        float gg = qp_bcast<0xAA>(act);
        float go = qp_bcast<0xFF>(act);

        c = fmaf(gf, c, gi * gg);
        float e2 = __builtin_amdgcn_exp2f(c * (-2.0f * L2E));
        float rr = __builtin_amdgcn_rcpf(1.0f + e2);
        float th = fmaf(2.0f, rr, -1.0f);   // tanh(c)
        float h  = go * th;

        hw[u] = h;                    // all 4 lanes, same addr, identical bits
        __syncthreads();              // the ONLY barrier per step
    };

    for (int k = 0; k < PRED_LEN; ++k) {
        for (int t = 0; t < SEQ_LEN; t += 2) {
            step(k + t,     hb0, hb1);
            step(k + t + 1, hb1, hb0);
        }
        // after 96 steps the latest h is in hb0

        // ---- prediction head: lanes 0..6 (no division anywhere) ----
        if (tid < FEAT) {
            float p0 = fcb[tid], p1 = 0.0f, p2 = 0.0f, p3 = 0.0f;
            const float4* hh = (const float4*)hb0;
            #pragma unroll
            for (int j = 0; j < 16; ++j) {
                float4 hv = hh[j];
                p0 = fmaf(fcw[tid * HIDDEN + 4*j + 0], hv.x, p0);
                p1 = fmaf(fcw[tid * HIDDEN + 4*j + 1], hv.y, p1);
                p2 = fmaf(fcw[tid * HIDDEN + 4*j + 2], hv.z, p2);
                p3 = fmaf(fcw[tid * HIDDEN + 4*j + 3], hv.w, p3);
            }
            float pred = (p0 + p1) + (p2 + p3);
            out[(b * PRED_LEN + k) * FEAT + tid] = pred;
            xs[(SEQ_LEN + k) * XSTR + tid] = pred;   // append (pad slot stays 0)
        }
        __syncthreads();
    }
}

extern "C" void kernel_launch(void* const* d_in, const int* in_sizes, int n_in,
                              void* d_out, int out_size, void* d_ws, size_t ws_size,
                              hipStream_t stream) {
    const float* x    = (const float*)d_in[0];
    const float* W_ih = (const float*)d_in[1];
    const float* W_hh = (const float*)d_in[2];
    const float* b_ih = (const float*)d_in[3];
    const float* b_hh = (const float*)d_in[4];
    const float* fc_W = (const float*)d_in[5];
    const float* fc_b = (const float*)d_in[6];
    float* out = (float*)d_out;

    lstm_ar_kernel<<<BATCH, 256, 0, stream>>>(x, W_ih, W_hh, b_ih, b_hh, fc_W, fc_b, out);
}

// Round 7
// 567.637 us; speedup vs baseline: 2.1585x; 1.0829x over previous
//
#include <hip/hip_runtime.h>

#define SEQ_LEN 96
#define PRED_LEN 16
#define HIDDEN 64
#define FEAT 7
#define BATCH 512
#define TL (SEQ_LEN + PRED_LEN)   // 112-row sliding timeline
#define XSTR 8                    // padded row stride

typedef float v2f __attribute__((ext_vector_type(2)));

#define L2E 1.4426950408889634f

// DPP pair-swap (0<->1, 2<->3, ...): quad_perm [1,0,3,2]. Pure VALU.
__device__ __forceinline__ float qp_xor1(float v) {
    return __int_as_float(__builtin_amdgcn_mov_dpp(__float_as_int(v), 0xB1, 0xF, 0xF, true));
}

// Block = 128 threads (2 waves) = ONE batch element; grid 512 -> 2 blocks/CU
// = 4 waves/CU = **1 wave per SIMD** (the r6 lesson: issue cost per SIMD =
// waves/SIMD x insts; at sigma=4 we paid everything twice). Thread (u=tid>>1,
// s=tid&1): all 4 gates of unit u over K-half [32s, 32s+32). 128 weight
// floats/thread as v2f -> v_pk_fma_f32. Gate split per lane: s=0 activates
// (f,o), s=1 activates (i,g) -- act_a (f|i) is sigmoid in BOTH lanes. One DPP
// pair-reduce round, 2 DPP exchanges, in-lane cell update, ONE barrier/step
// (parity ping-pong hb0/hb1).
__global__ __launch_bounds__(128)
__attribute__((amdgpu_waves_per_eu(1, 1)))
void lstm_ar_kernel(
    const float* __restrict__ x,     // [B, 96, 7]
    const float* __restrict__ W_ih,  // [256, 7]
    const float* __restrict__ W_hh,  // [256, 64]
    const float* __restrict__ b_ih,  // [256]
    const float* __restrict__ b_hh,  // [256]
    const float* __restrict__ fc_W,  // [7, 64]
    const float* __restrict__ fc_b,  // [7]
    float* __restrict__ out)         // [B, 16, 7]
{
    __shared__ float xs[TL * XSTR];   // padded sliding timeline (pad slot = 0)
    __shared__ float hb0[HIDDEN];     // h ping-pong
    __shared__ float hb1[HIDDEN];
    __shared__ float fcw[FEAT * HIDDEN];
    __shared__ float fcb[FEAT];

    const int tid = threadIdx.x;
    const int b   = blockIdx.x;
    const int u   = tid >> 1;         // hidden unit 0..63
    const int s   = tid & 1;          // K-half / activation-role

    // ---- per-thread weights: 4 gates x 32 K-cols as 16 v2f each ----
    v2f wh[4][16];
    #pragma unroll
    for (int g = 0; g < 4; ++g) {
        const float* wr = W_hh + (u + (g << 6)) * HIDDEN + (s << 5);
        #pragma unroll
        for (int j = 0; j < 16; ++j) wh[g][j] = *(const v2f*)(wr + 2 * j);
    }
    v2f wx[4][2];                     // x-cols [4s, 4s+4); col 7 -> 0 (eats pad)
    #pragma unroll
    for (int g = 0; g < 4; ++g)
        #pragma unroll
        for (int i = 0; i < 2; ++i) {
            int c0 = (s << 2) + 2 * i, c1 = c0 + 1;
            wx[g][i].x = W_ih[(u + (g << 6)) * FEAT + c0];
            wx[g][i].y = (c1 < FEAT) ? W_ih[(u + (g << 6)) * FEAT + c1] : 0.0f;
        }
    float bias[4];                    // bias carried by s==0 only
    #pragma unroll
    for (int g = 0; g < 4; ++g)
        bias[g] = (s == 0) ? (b_ih[u + (g << 6)] + b_hh[u + (g << 6)]) : 0.0f;

    // act_b per-lane consts: s=0 -> gate o (sigmoid), s=1 -> gate g (tanh)
    const float bk = (s == 1) ? (-2.0f * L2E) : (-L2E);
    const float bm = (s == 1) ? 2.0f : 1.0f;
    const float bbc = (s == 1) ? -1.0f : 0.0f;

    // ---- stage timeline / fc / init ----
    for (int i = tid; i < TL * XSTR; i += 128) {
        int row = i >> 3, f = i & 7;
        float v = 0.0f;
        if (row < SEQ_LEN && f < FEAT) v = x[b * SEQ_LEN * FEAT + row * FEAT + f];
        xs[i] = v;
    }
    for (int i = tid; i < FEAT * HIDDEN; i += 128) fcw[i] = fc_W[i];
    if (tid < FEAT)   fcb[tid] = fc_b[tid];
    if (tid < HIDDEN) hb0[tid] = 0.0f;
    float c = 0.0f;                   // c_u replica (identical in both pair lanes)
    __syncthreads();

    auto step = [&](int row, const float* __restrict__ hr, float* __restrict__ hw) {
        const float4* xp = (const float4*)(xs + row * XSTR + (s << 2));
        float4 xv = xp[0];
        const float4* h4 = (const float4*)(hr + (s << 5));

        v2f A0, A1, A2, A3;
        A0.x = bias[0]; A0.y = 0.0f;
        A1.x = bias[1]; A1.y = 0.0f;
        A2.x = bias[2]; A2.y = 0.0f;
        A3.x = bias[3]; A3.y = 0.0f;
        v2f xlo; xlo.x = xv.x; xlo.y = xv.y;
        v2f xhi; xhi.x = xv.z; xhi.y = xv.w;
        A0 = __builtin_elementwise_fma(wx[0][0], xlo, A0);
        A1 = __builtin_elementwise_fma(wx[1][0], xlo, A1);
        A2 = __builtin_elementwise_fma(wx[2][0], xlo, A2);
        A3 = __builtin_elementwise_fma(wx[3][0], xlo, A3);
        A0 = __builtin_elementwise_fma(wx[0][1], xhi, A0);
        A1 = __builtin_elementwise_fma(wx[1][1], xhi, A1);
        A2 = __builtin_elementwise_fma(wx[2][1], xhi, A2);
        A3 = __builtin_elementwise_fma(wx[3][1], xhi, A3);

        #pragma unroll
        for (int j = 0; j < 8; ++j) {
            float4 hv = h4[j];
            v2f hlo; hlo.x = hv.x; hlo.y = hv.y;
            v2f hhi; hhi.x = hv.z; hhi.y = hv.w;
            A0 = __builtin_elementwise_fma(wh[0][2*j],   hlo, A0);
            A1 = __builtin_elementwise_fma(wh[1][2*j],   hlo, A1);
            A2 = __builtin_elementwise_fma(wh[2][2*j],   hlo, A2);
            A3 = __builtin_elementwise_fma(wh[3][2*j],   hlo, A3);
            A0 = __builtin_elementwise_fma(wh[0][2*j+1], hhi, A0);
            A1 = __builtin_elementwise_fma(wh[1][2*j+1], hhi, A1);
            A2 = __builtin_elementwise_fma(wh[2][2*j+1], hhi, A2);
            A3 = __builtin_elementwise_fma(wh[3][2*j+1], hhi, A3);
        }

        // horizontal + ONE pair-reduce round: both lanes get all 4 gate sums
        float r0 = A0.x + A0.y, r1 = A1.x + A1.y;
        float r2 = A2.x + A2.y, r3 = A3.x + A3.y;
        r0 += qp_xor1(r0); r1 += qp_xor1(r1);
        r2 += qp_xor1(r2); r3 += qp_xor1(r3);

        // lane roles: s=0 activates f(r1),o(r3); s=1 activates i(r0),g(r2)
        float aa = s ? r0 : r1;                       // sigmoid in both lanes
        float ab = s ? r2 : r3;                       // tanh | sigmoid
        float ea = __builtin_amdgcn_exp2f(aa * (-L2E));
        float va = __builtin_amdgcn_rcpf(1.0f + ea);  // sigmoid(aa)
        float eb = __builtin_amdgcn_exp2f(ab * bk);
        float rb = __builtin_amdgcn_rcpf(1.0f + eb);
        float vb = fmaf(bm, rb, bbc);

        // exchange with partner lane, canonicalize (i,f,g,o)
        float pa = qp_xor1(va);
        float pb = qp_xor1(vb);
        float gi = s ? va : pa;
        float gf = s ? pa : va;
        float gg = s ? vb : pb;
        float go = s ? pb : vb;

        c = fmaf(gf, c, gi * gg);
        float e2 = __builtin_amdgcn_exp2f(c * (-2.0f * L2E));
        float rr = __builtin_amdgcn_rcpf(1.0f + e2);
        float th = fmaf(2.0f, rr, -1.0f);             // tanh(c)
        float h  = go * th;

        hw[u] = h;                  // both pair lanes: same addr, identical bits
        __syncthreads();            // the ONLY barrier per step
    };

    for (int k = 0; k < PRED_LEN; ++k) {
        for (int t = 0; t < SEQ_LEN; t += 2) {
            step(k + t,     hb0, hb1);
            step(k + t + 1, hb1, hb0);
        }
        // after 96 steps the latest h is in hb0

        // ---- prediction head: lanes 0..6 of wave 0 ----
        if (tid < FEAT) {
            float p0 = fcb[tid], p1 = 0.0f, p2 = 0.0f, p3 = 0.0f;
            const float4* hh = (const float4*)hb0;
            #pragma unroll
            for (int j = 0; j < 16; ++j) {
                float4 hv = hh[j];
                p0 = fmaf(fcw[tid * HIDDEN + 4*j + 0], hv.x, p0);
                p1 = fmaf(fcw[tid * HIDDEN + 4*j + 1], hv.y, p1);
                p2 = fmaf(fcw[tid * HIDDEN + 4*j + 2], hv.z, p2);
                p3 = fmaf(fcw[tid * HIDDEN + 4*j + 3], hv.w, p3);
            }
            float pred = (p0 + p1) + (p2 + p3);
            out[(b * PRED_LEN + k) * FEAT + tid] = pred;
            xs[(SEQ_LEN + k) * XSTR + tid] = pred;   // append (pad slot stays 0)
        }
        __syncthreads();
    }
}

extern "C" void kernel_launch(void* const* d_in, const int* in_sizes, int n_in,
                              void* d_out, int out_size, void* d_ws, size_t ws_size,
                              hipStream_t stream) {
    const float* x    = (const float*)d_in[0];
    const float* W_ih = (const float*)d_in[1];
    const float* W_hh = (const float*)d_in[2];
    const float* b_ih = (const float*)d_in[3];
    const float* b_hh = (const float*)d_in[4];
    const float* fc_W = (const float*)d_in[5];
    const float* fc_b = (const float*)d_in[6];
    float* out = (float*)d_out;

    lstm_ar_kernel<<<BATCH, 128, 0, stream>>>(x, W_ih, W_hh, b_ih, b_hh, fc_W, fc_b, out);
}